// Round 1
// baseline (2917.989 us; speedup 1.0000x reference)
//
#include <hip/hip_runtime.h>

#define K_DIM 256

// ---- degree count: deg[idx[i]] += 1 ----
__global__ void degree_kernel(const int* __restrict__ idx, int* __restrict__ deg, int E) {
    int i = blockIdx.x * blockDim.x + threadIdx.x;
    if (i < E) atomicAdd(&deg[idx[i]], 1);
}

// ---- edge scatter: agg[dst[e]] += feat[src[e]] * rsqrt(max(out_deg[src[e]],1)) ----
// One wave (64 lanes) per edge, float4 per lane (64*4 = 256 features).
__global__ void scatter_kernel(const float* __restrict__ feat,
                               const int* __restrict__ src,
                               const int* __restrict__ dst,
                               const int* __restrict__ out_deg,
                               float* __restrict__ agg, int E) {
    int t = blockIdx.x * blockDim.x + threadIdx.x;
    int e = t >> 6;
    int lane = t & 63;
    if (e >= E) return;
    int s = src[e];
    int d = dst[e];
    float ns = rsqrtf((float)max(out_deg[s], 1));
    const float4 v = *reinterpret_cast<const float4*>(feat + ((size_t)s * K_DIM + lane * 4));
    float* o = agg + ((size_t)d * K_DIM + lane * 4);
    atomicAdd(o + 0, v.x * ns);
    atomicAdd(o + 1, v.y * ns);
    atomicAdd(o + 2, v.z * ns);
    atomicAdd(o + 3, v.w * ns);
}

// ---- fused row-scale + GEMM + bias (+relu): out = act((A*rsqrt(in_deg)) @ W + b) ----
// Block of NCOLS threads handles 16 rows; A rows staged in LDS (broadcast reads),
// W streamed coalesced from L2 (reused 16x per load).
template <int NCOLS, bool RELU>
__global__ void gemm_kernel(const float* __restrict__ A,      // [M, 256]
                            const int* __restrict__ in_deg,   // [M]
                            const float* __restrict__ W,      // [256, NCOLS]
                            const float* __restrict__ bias,   // [NCOLS]
                            float* __restrict__ out,          // [M, NCOLS]
                            int M) {
    constexpr int ROWS = 16;
    __shared__ float As[ROWS][K_DIM];
    __shared__ float sScale[ROWS];
    const int row0 = blockIdx.x * ROWS;
    const int tid = threadIdx.x;

    if (tid < ROWS) {
        int r = row0 + tid;
        sScale[tid] = (r < M) ? rsqrtf((float)max(in_deg[r], 1)) : 0.0f;
    }
    __syncthreads();
    for (int i = tid; i < ROWS * K_DIM; i += NCOLS) {
        int r = i >> 8;                 // K_DIM == 256
        int k = i & (K_DIM - 1);
        int row = row0 + r;
        As[r][k] = (row < M) ? A[(size_t)row * K_DIM + k] * sScale[r] : 0.0f;
    }
    __syncthreads();

    float acc[ROWS];
#pragma unroll
    for (int r = 0; r < ROWS; ++r) acc[r] = 0.0f;

    const int c = tid;
    for (int k = 0; k < K_DIM; k += 4) {
        float w0 = W[(size_t)(k + 0) * NCOLS + c];
        float w1 = W[(size_t)(k + 1) * NCOLS + c];
        float w2 = W[(size_t)(k + 2) * NCOLS + c];
        float w3 = W[(size_t)(k + 3) * NCOLS + c];
#pragma unroll
        for (int r = 0; r < ROWS; ++r) {
            const float4 a = *reinterpret_cast<const float4*>(&As[r][k]);
            acc[r] = fmaf(a.x, w0, acc[r]);
            acc[r] = fmaf(a.y, w1, acc[r]);
            acc[r] = fmaf(a.z, w2, acc[r]);
            acc[r] = fmaf(a.w, w3, acc[r]);
        }
    }

    const float b = bias[c];
#pragma unroll
    for (int r = 0; r < ROWS; ++r) {
        int row = row0 + r;
        if (row < M) {
            float v = acc[r] + b;
            if (RELU) v = fmaxf(v, 0.0f);
            out[(size_t)row * NCOLS + c] = v;
        }
    }
}

extern "C" void kernel_launch(void* const* d_in, const int* in_sizes, int n_in,
                              void* d_out, int out_size, void* d_ws, size_t ws_size,
                              hipStream_t stream) {
    const float* features = (const float*)d_in[0];
    const float* W1 = (const float*)d_in[1];
    const float* b1 = (const float*)d_in[2];
    const float* W2 = (const float*)d_in[3];
    const float* b2 = (const float*)d_in[4];
    const int* src0 = (const int*)d_in[5];
    const int* dst0 = (const int*)d_in[6];
    const int* src1 = (const int*)d_in[7];
    const int* dst1 = (const int*)d_in[8];
    const int E0 = in_sizes[5];
    const int E1 = in_sizes[7];
    const int NSRC0 = 100000, NDST0 = 20000, NDST1 = 4096;

    char* ws = (char*)d_ws;
    size_t off = 0;
    auto carve = [&](size_t bytes) -> void* {
        void* p = ws + off;
        off = (off + bytes + 255) & ~(size_t)255;
        return p;
    };
    int* out_deg0 = (int*)carve((size_t)NSRC0 * 4);
    int* in_deg0  = (int*)carve((size_t)NDST0 * 4);
    int* out_deg1 = (int*)carve((size_t)NDST0 * 4);
    int* in_deg1  = (int*)carve((size_t)NDST1 * 4);
    float* agg0 = (float*)carve((size_t)NDST0 * K_DIM * 4);
    float* xbuf = (float*)carve((size_t)NDST0 * K_DIM * 4);
    float* agg1 = (float*)carve((size_t)NDST1 * K_DIM * 4);
    (void)ws_size; (void)n_in; (void)out_size;

    // zero accumulators (ws is poisoned 0xAA before every call)
    hipMemsetAsync(out_deg0, 0, (size_t)NSRC0 * 4, stream);
    hipMemsetAsync(in_deg0, 0, (size_t)NDST0 * 4, stream);
    hipMemsetAsync(out_deg1, 0, (size_t)NDST0 * 4, stream);
    hipMemsetAsync(in_deg1, 0, (size_t)NDST1 * 4, stream);
    hipMemsetAsync(agg0, 0, (size_t)NDST0 * K_DIM * 4, stream);
    hipMemsetAsync(agg1, 0, (size_t)NDST1 * K_DIM * 4, stream);

    // degrees
    degree_kernel<<<(E0 + 255) / 256, 256, 0, stream>>>(src0, out_deg0, E0);
    degree_kernel<<<(E0 + 255) / 256, 256, 0, stream>>>(dst0, in_deg0, E0);
    degree_kernel<<<(E1 + 255) / 256, 256, 0, stream>>>(src1, out_deg1, E1);
    degree_kernel<<<(E1 + 255) / 256, 256, 0, stream>>>(dst1, in_deg1, E1);

    // layer 0: scatter-aggregate then GEMM(+bias+relu)
    {
        long long threads = (long long)E0 * 64;
        int blocks = (int)((threads + 255) / 256);
        scatter_kernel<<<blocks, 256, 0, stream>>>(features, src0, dst0, out_deg0, agg0, E0);
    }
    gemm_kernel<256, true><<<(NDST0 + 15) / 16, 256, 0, stream>>>(agg0, in_deg0, W1, b1, xbuf, NDST0);

    // layer 1: scatter-aggregate then GEMM(+bias)
    {
        long long threads = (long long)E1 * 64;
        int blocks = (int)((threads + 255) / 256);
        scatter_kernel<<<blocks, 256, 0, stream>>>(xbuf, src1, dst1, out_deg1, agg1, E1);
    }
    gemm_kernel<128, false><<<(NDST1 + 15) / 16, 128, 0, stream>>>(agg1, in_deg1, W2, b2, (float*)d_out, NDST1);
}

// Round 2
// 542.825 us; speedup vs baseline: 5.3756x; 5.3756x over previous
//
#include <hip/hip_runtime.h>

#define K_DIM 256

// ---- degree count: deg[idx[i]] += 1 ----
__global__ void degree_kernel(const int* __restrict__ idx, int* __restrict__ deg, int E) {
    int i = blockIdx.x * blockDim.x + threadIdx.x;
    if (i < E) atomicAdd(&deg[idx[i]], 1);
}

// ---- single-block exclusive scan: offs[i]=sum_{j<i}deg[j]; offs[n]=total; cursor=offs ----
__global__ void scan_kernel(const int* __restrict__ deg, int* __restrict__ offs,
                            int* __restrict__ cursor, int n) {
    __shared__ int smem[1024];
    __shared__ int running;
    const int tid = threadIdx.x;
    if (tid == 0) running = 0;
    __syncthreads();
    for (int base = 0; base < n; base += 1024) {
        int i = base + tid;
        int v = (i < n) ? deg[i] : 0;
        smem[tid] = v;
        __syncthreads();
        for (int s = 1; s < 1024; s <<= 1) {
            int t = (tid >= s) ? smem[tid - s] : 0;
            __syncthreads();
            smem[tid] += t;
            __syncthreads();
        }
        int excl = smem[tid] - v + running;
        if (i < n) { offs[i] = excl; cursor[i] = excl; }
        int total = smem[1023];
        __syncthreads();
        if (tid == 0) running += total;
        __syncthreads();
    }
    if (tid == 0) offs[n] = running;
}

// ---- CSR fill: slot = cursor[dst[e]]++; esrc[slot] = src[e] ----
__global__ void csr_fill_kernel(const int* __restrict__ src, const int* __restrict__ dst,
                                int* __restrict__ cursor, int* __restrict__ esrc, int E) {
    int e = blockIdx.x * blockDim.x + threadIdx.x;
    if (e < E) {
        int slot = atomicAdd(&cursor[dst[e]], 1);
        esrc[slot] = src[e];
    }
}

// ---- gather-sum: one wave per dst row; out[row] = norm_dst * sum_e feat[src_e]*norm_src ----
__global__ __launch_bounds__(256) void gather_kernel(
        const float* __restrict__ feat, const int* __restrict__ esrc,
        const int* __restrict__ offs, const int* __restrict__ out_deg,
        const int* __restrict__ in_deg, float* __restrict__ outbuf, int n_dst) {
    int wave = blockIdx.x * (blockDim.x >> 6) + (threadIdx.x >> 6);
    int lane = threadIdx.x & 63;
    if (wave >= n_dst) return;
    const int beg = offs[wave];
    const int end = offs[wave + 1];
    float4 acc0 = {0.f, 0.f, 0.f, 0.f};
    float4 acc1 = {0.f, 0.f, 0.f, 0.f};
    int i = beg;
    for (; i + 1 < end; i += 2) {
        int s0 = esrc[i];
        int s1 = esrc[i + 1];
        float n0 = rsqrtf((float)max(out_deg[s0], 1));
        float n1 = rsqrtf((float)max(out_deg[s1], 1));
        const float4 v0 = *reinterpret_cast<const float4*>(feat + ((size_t)s0 * K_DIM + lane * 4));
        const float4 v1 = *reinterpret_cast<const float4*>(feat + ((size_t)s1 * K_DIM + lane * 4));
        acc0.x = fmaf(v0.x, n0, acc0.x); acc0.y = fmaf(v0.y, n0, acc0.y);
        acc0.z = fmaf(v0.z, n0, acc0.z); acc0.w = fmaf(v0.w, n0, acc0.w);
        acc1.x = fmaf(v1.x, n1, acc1.x); acc1.y = fmaf(v1.y, n1, acc1.y);
        acc1.z = fmaf(v1.z, n1, acc1.z); acc1.w = fmaf(v1.w, n1, acc1.w);
    }
    if (i < end) {
        int s0 = esrc[i];
        float n0 = rsqrtf((float)max(out_deg[s0], 1));
        const float4 v0 = *reinterpret_cast<const float4*>(feat + ((size_t)s0 * K_DIM + lane * 4));
        acc0.x = fmaf(v0.x, n0, acc0.x); acc0.y = fmaf(v0.y, n0, acc0.y);
        acc0.z = fmaf(v0.z, n0, acc0.z); acc0.w = fmaf(v0.w, n0, acc0.w);
    }
    float nd = rsqrtf((float)max(in_deg[wave], 1));
    float4 o;
    o.x = (acc0.x + acc1.x) * nd;
    o.y = (acc0.y + acc1.y) * nd;
    o.z = (acc0.z + acc1.z) * nd;
    o.w = (acc0.w + acc1.w) * nd;
    *reinterpret_cast<float4*>(outbuf + ((size_t)wave * K_DIM + lane * 4)) = o;
}

// ---- GEMM + bias (+relu): out = act(A @ W + b); A already normalized ----
template <int NCOLS, bool RELU>
__global__ void gemm_kernel(const float* __restrict__ A,      // [M, 256]
                            const float* __restrict__ W,      // [256, NCOLS]
                            const float* __restrict__ bias,   // [NCOLS]
                            float* __restrict__ out,          // [M, NCOLS]
                            int M) {
    constexpr int ROWS = 16;
    __shared__ float As[ROWS][K_DIM];
    const int row0 = blockIdx.x * ROWS;
    const int tid = threadIdx.x;

    for (int i = tid; i < ROWS * K_DIM; i += NCOLS) {
        int r = i >> 8;                 // K_DIM == 256
        int k = i & (K_DIM - 1);
        int row = row0 + r;
        As[r][k] = (row < M) ? A[(size_t)row * K_DIM + k] : 0.0f;
    }
    __syncthreads();

    float acc[ROWS];
#pragma unroll
    for (int r = 0; r < ROWS; ++r) acc[r] = 0.0f;

    const int c = tid;
    for (int k = 0; k < K_DIM; k += 4) {
        float w0 = W[(size_t)(k + 0) * NCOLS + c];
        float w1 = W[(size_t)(k + 1) * NCOLS + c];
        float w2 = W[(size_t)(k + 2) * NCOLS + c];
        float w3 = W[(size_t)(k + 3) * NCOLS + c];
#pragma unroll
        for (int r = 0; r < ROWS; ++r) {
            const float4 a = *reinterpret_cast<const float4*>(&As[r][k]);
            acc[r] = fmaf(a.x, w0, acc[r]);
            acc[r] = fmaf(a.y, w1, acc[r]);
            acc[r] = fmaf(a.z, w2, acc[r]);
            acc[r] = fmaf(a.w, w3, acc[r]);
        }
    }

    const float b = bias[c];
#pragma unroll
    for (int r = 0; r < ROWS; ++r) {
        int row = row0 + r;
        if (row < M) {
            float v = acc[r] + b;
            if (RELU) v = fmaxf(v, 0.0f);
            out[(size_t)row * NCOLS + c] = v;
        }
    }
}

extern "C" void kernel_launch(void* const* d_in, const int* in_sizes, int n_in,
                              void* d_out, int out_size, void* d_ws, size_t ws_size,
                              hipStream_t stream) {
    const float* features = (const float*)d_in[0];
    const float* W1 = (const float*)d_in[1];
    const float* b1 = (const float*)d_in[2];
    const float* W2 = (const float*)d_in[3];
    const float* b2 = (const float*)d_in[4];
    const int* src0 = (const int*)d_in[5];
    const int* dst0 = (const int*)d_in[6];
    const int* src1 = (const int*)d_in[7];
    const int* dst1 = (const int*)d_in[8];
    const int E0 = in_sizes[5];
    const int E1 = in_sizes[7];
    const int NSRC0 = 100000, NDST0 = 20000, NDST1 = 4096;

    char* ws = (char*)d_ws;
    size_t off = 0;
    auto carve = [&](size_t bytes) -> void* {
        void* p = ws + off;
        off = (off + bytes + 255) & ~(size_t)255;
        return p;
    };
    int* out_deg0 = (int*)carve((size_t)NSRC0 * 4);
    int* in_deg0  = (int*)carve((size_t)NDST0 * 4);
    int* out_deg1 = (int*)carve((size_t)NDST0 * 4);
    int* in_deg1  = (int*)carve((size_t)NDST1 * 4);
    int* offs0    = (int*)carve((size_t)(NDST0 + 1) * 4);
    int* cursor0  = (int*)carve((size_t)NDST0 * 4);
    int* offs1    = (int*)carve((size_t)(NDST1 + 1) * 4);
    int* cursor1  = (int*)carve((size_t)NDST1 * 4);
    int* esrc0    = (int*)carve((size_t)E0 * 4);
    int* esrc1    = (int*)carve((size_t)E1 * 4);
    float* agg0 = (float*)carve((size_t)NDST0 * K_DIM * 4);
    float* xbuf = (float*)carve((size_t)NDST0 * K_DIM * 4);
    float* agg1 = (float*)carve((size_t)NDST1 * K_DIM * 4);
    (void)ws_size; (void)n_in; (void)out_size;

    // zero degree counters (ws is poisoned 0xAA before every call)
    hipMemsetAsync(out_deg0, 0, (size_t)NSRC0 * 4, stream);
    hipMemsetAsync(in_deg0, 0, (size_t)NDST0 * 4, stream);
    hipMemsetAsync(out_deg1, 0, (size_t)NDST0 * 4, stream);
    hipMemsetAsync(in_deg1, 0, (size_t)NDST1 * 4, stream);

    // degrees
    degree_kernel<<<(E0 + 255) / 256, 256, 0, stream>>>(src0, out_deg0, E0);
    degree_kernel<<<(E0 + 255) / 256, 256, 0, stream>>>(dst0, in_deg0, E0);
    degree_kernel<<<(E1 + 255) / 256, 256, 0, stream>>>(src1, out_deg1, E1);
    degree_kernel<<<(E1 + 255) / 256, 256, 0, stream>>>(dst1, in_deg1, E1);

    // CSR by dst (deterministic per call)
    scan_kernel<<<1, 1024, 0, stream>>>(in_deg0, offs0, cursor0, NDST0);
    scan_kernel<<<1, 1024, 0, stream>>>(in_deg1, offs1, cursor1, NDST1);
    csr_fill_kernel<<<(E0 + 255) / 256, 256, 0, stream>>>(src0, dst0, cursor0, esrc0, E0);
    csr_fill_kernel<<<(E1 + 255) / 256, 256, 0, stream>>>(src1, dst1, cursor1, esrc1, E1);

    // layer 0: gather-aggregate (norms fused) then GEMM(+bias+relu)
    gather_kernel<<<(NDST0 + 3) / 4, 256, 0, stream>>>(features, esrc0, offs0, out_deg0,
                                                       in_deg0, agg0, NDST0);
    gemm_kernel<256, true><<<(NDST0 + 15) / 16, 256, 0, stream>>>(agg0, W1, b1, xbuf, NDST0);

    // layer 1: gather-aggregate then GEMM(+bias)
    gather_kernel<<<(NDST1 + 3) / 4, 256, 0, stream>>>(xbuf, esrc1, offs1, out_deg1,
                                                       in_deg1, agg1, NDST1);
    gemm_kernel<128, false><<<(NDST1 + 15) / 16, 128, 0, stream>>>(agg1, W2, b2, (float*)d_out, NDST1);
}

// Round 3
// 490.332 us; speedup vs baseline: 5.9510x; 1.1071x over previous
//
#include <hip/hip_runtime.h>

#define K_DIM 256

// ---- fused degree count over all four index arrays ----
// E0, E1 are multiples of 256, so branches are wave-uniform.
__global__ void degree4_kernel(const int* __restrict__ src0, const int* __restrict__ dst0,
                               const int* __restrict__ src1, const int* __restrict__ dst1,
                               int* __restrict__ od0, int* __restrict__ id0,
                               int* __restrict__ od1, int* __restrict__ id1,
                               int E0, int E1) {
    int i = blockIdx.x * blockDim.x + threadIdx.x;
    if (i < E0) {
        atomicAdd(&od0[src0[i]], 1);
    } else if (i < 2 * E0) {
        atomicAdd(&id0[dst0[i - E0]], 1);
    } else if (i < 2 * E0 + E1) {
        atomicAdd(&od1[src1[i - 2 * E0]], 1);
    } else if (i < 2 * E0 + 2 * E1) {
        atomicAdd(&id1[dst1[i - 2 * E0 - E1]], 1);
    }
}

// ---- exclusive scan, shfl-based: block b scans array b ----
// 1024 threads = 16 waves; per 1024-chunk: wave shfl-scan (no barriers) + one
// cross-wave LDS combine. 4 barriers/iter vs 20 for naive Hillis-Steele.
__global__ __launch_bounds__(1024) void scan2_kernel(
        const int* __restrict__ deg0, int* __restrict__ offs0, int* __restrict__ cur0, int n0,
        const int* __restrict__ deg1, int* __restrict__ offs1, int* __restrict__ cur1, int n1) {
    const int* deg = (blockIdx.x == 0) ? deg0 : deg1;
    int* offs      = (blockIdx.x == 0) ? offs0 : offs1;
    int* cur       = (blockIdx.x == 0) ? cur0 : cur1;
    const int n    = (blockIdx.x == 0) ? n0 : n1;

    __shared__ int wsums[16];
    __shared__ int sbtotal;
    __shared__ int srunning;
    const int tid = threadIdx.x;
    const int wid = tid >> 6;
    const int lane = tid & 63;
    if (tid == 0) srunning = 0;
    __syncthreads();

    for (int base = 0; base < n; base += 1024) {
        int i = base + tid;
        int v = (i < n) ? deg[i] : 0;
        // inclusive wave scan
        int x = v;
#pragma unroll
        for (int s = 1; s < 64; s <<= 1) {
            int t = __shfl_up(x, s, 64);
            if (lane >= s) x += t;
        }
        if (lane == 63) wsums[wid] = x;
        __syncthreads();                       // (1) wsums visible
        if (wid == 0) {
            int wv = (lane < 16) ? wsums[lane] : 0;
            int wx = wv;
#pragma unroll
            for (int s = 1; s < 16; s <<= 1) {
                int t = __shfl_up(wx, s, 64);
                if (lane >= s) wx += t;
            }
            if (lane < 16) wsums[lane] = wx - wv;   // exclusive
            if (lane == 15) sbtotal = wx;           // chunk total
        }
        __syncthreads();                       // (2) wexcl + total visible
        int excl = x - v + wsums[wid] + srunning;
        if (i < n) { offs[i] = excl; cur[i] = excl; }
        __syncthreads();                       // (3) all reads of srunning done
        if (tid == 0) srunning += sbtotal;
        __syncthreads();                       // (4) srunning updated before reuse
    }
    if (tid == 0) offs[n] = srunning;
}

// ---- fused CSR fill: slot = cursor[dst[e]]++; esrc[slot] = src[e] ----
__global__ void fill2_kernel(const int* __restrict__ src0, const int* __restrict__ dst0,
                             int* __restrict__ cur0, int* __restrict__ esrc0, int E0,
                             const int* __restrict__ src1, const int* __restrict__ dst1,
                             int* __restrict__ cur1, int* __restrict__ esrc1, int E1) {
    int i = blockIdx.x * blockDim.x + threadIdx.x;
    if (i < E0) {
        int slot = atomicAdd(&cur0[dst0[i]], 1);
        esrc0[slot] = src0[i];
    } else if (i < E0 + E1) {
        int e = i - E0;
        int slot = atomicAdd(&cur1[dst1[e]], 1);
        esrc1[slot] = src1[e];
    }
}

// ---- gather-sum: one wave per dst row; out[row] = norm_dst * sum_e feat[src_e]*norm_src ----
__global__ __launch_bounds__(256) void gather_kernel(
        const float* __restrict__ feat, const int* __restrict__ esrc,
        const int* __restrict__ offs, const int* __restrict__ out_deg,
        const int* __restrict__ in_deg, float* __restrict__ outbuf, int n_dst) {
    int wave = blockIdx.x * (blockDim.x >> 6) + (threadIdx.x >> 6);
    int lane = threadIdx.x & 63;
    if (wave >= n_dst) return;
    const int beg = offs[wave];
    const int end = offs[wave + 1];
    float4 acc0 = {0.f, 0.f, 0.f, 0.f};
    float4 acc1 = {0.f, 0.f, 0.f, 0.f};
    int i = beg;
    for (; i + 1 < end; i += 2) {
        int s0 = esrc[i];
        int s1 = esrc[i + 1];
        float n0 = rsqrtf((float)max(out_deg[s0], 1));
        float n1 = rsqrtf((float)max(out_deg[s1], 1));
        const float4 v0 = *reinterpret_cast<const float4*>(feat + ((size_t)s0 * K_DIM + lane * 4));
        const float4 v1 = *reinterpret_cast<const float4*>(feat + ((size_t)s1 * K_DIM + lane * 4));
        acc0.x = fmaf(v0.x, n0, acc0.x); acc0.y = fmaf(v0.y, n0, acc0.y);
        acc0.z = fmaf(v0.z, n0, acc0.z); acc0.w = fmaf(v0.w, n0, acc0.w);
        acc1.x = fmaf(v1.x, n1, acc1.x); acc1.y = fmaf(v1.y, n1, acc1.y);
        acc1.z = fmaf(v1.z, n1, acc1.z); acc1.w = fmaf(v1.w, n1, acc1.w);
    }
    if (i < end) {
        int s0 = esrc[i];
        float n0 = rsqrtf((float)max(out_deg[s0], 1));
        const float4 v0 = *reinterpret_cast<const float4*>(feat + ((size_t)s0 * K_DIM + lane * 4));
        acc0.x = fmaf(v0.x, n0, acc0.x); acc0.y = fmaf(v0.y, n0, acc0.y);
        acc0.z = fmaf(v0.z, n0, acc0.z); acc0.w = fmaf(v0.w, n0, acc0.w);
    }
    float nd = rsqrtf((float)max(in_deg[wave], 1));
    float4 o;
    o.x = (acc0.x + acc1.x) * nd;
    o.y = (acc0.y + acc1.y) * nd;
    o.z = (acc0.z + acc1.z) * nd;
    o.w = (acc0.w + acc1.w) * nd;
    *reinterpret_cast<float4*>(outbuf + ((size_t)wave * K_DIM + lane * 4)) = o;
}

// ---- GEMM + bias (+relu), no LDS: A-tile reads are block-uniform -> scalar
// (s_load) path; W reads per-lane coalesced from L2 (256 KB, resident). ----
template <int NCOLS, bool RELU>
__global__ __launch_bounds__(NCOLS) void gemm_kernel(
        const float* __restrict__ A,      // [M, 256]
        const float* __restrict__ W,      // [256, NCOLS]
        const float* __restrict__ bias,   // [NCOLS]
        float* __restrict__ out,          // [M, NCOLS]
        int M) {
    constexpr int ROWS = 16;
    const int row0 = blockIdx.x * ROWS;   // M is a multiple of 16
    const int c = threadIdx.x;
    const float* __restrict__ Ablk = A + (size_t)row0 * K_DIM;

    float acc[ROWS];
#pragma unroll
    for (int r = 0; r < ROWS; ++r) acc[r] = 0.0f;

    for (int k = 0; k < K_DIM; k += 4) {
        float w0 = W[(size_t)(k + 0) * NCOLS + c];
        float w1 = W[(size_t)(k + 1) * NCOLS + c];
        float w2 = W[(size_t)(k + 2) * NCOLS + c];
        float w3 = W[(size_t)(k + 3) * NCOLS + c];
#pragma unroll
        for (int r = 0; r < ROWS; ++r) {
            const float4 a = *reinterpret_cast<const float4*>(Ablk + r * K_DIM + k);  // uniform
            acc[r] = fmaf(a.x, w0, acc[r]);
            acc[r] = fmaf(a.y, w1, acc[r]);
            acc[r] = fmaf(a.z, w2, acc[r]);
            acc[r] = fmaf(a.w, w3, acc[r]);
        }
    }

    const float b = bias[c];
#pragma unroll
    for (int r = 0; r < ROWS; ++r) {
        int row = row0 + r;
        if (row < M) {
            float v = acc[r] + b;
            if (RELU) v = fmaxf(v, 0.0f);
            out[(size_t)row * NCOLS + c] = v;
        }
    }
}

extern "C" void kernel_launch(void* const* d_in, const int* in_sizes, int n_in,
                              void* d_out, int out_size, void* d_ws, size_t ws_size,
                              hipStream_t stream) {
    const float* features = (const float*)d_in[0];
    const float* W1 = (const float*)d_in[1];
    const float* b1 = (const float*)d_in[2];
    const float* W2 = (const float*)d_in[3];
    const float* b2 = (const float*)d_in[4];
    const int* src0 = (const int*)d_in[5];
    const int* dst0 = (const int*)d_in[6];
    const int* src1 = (const int*)d_in[7];
    const int* dst1 = (const int*)d_in[8];
    const int E0 = in_sizes[5];
    const int E1 = in_sizes[7];
    const int NSRC0 = 100000, NDST0 = 20000, NDST1 = 4096;

    char* ws = (char*)d_ws;
    size_t off = 0;
    auto carve = [&](size_t bytes) -> void* {
        void* p = ws + off;
        off = (off + bytes + 255) & ~(size_t)255;
        return p;
    };
    // degree buffers first -> one contiguous memset
    int* out_deg0 = (int*)carve((size_t)NSRC0 * 4);
    int* in_deg0  = (int*)carve((size_t)NDST0 * 4);
    int* out_deg1 = (int*)carve((size_t)NDST0 * 4);
    int* in_deg1  = (int*)carve((size_t)NDST1 * 4);
    const size_t deg_span = off;
    int* offs0    = (int*)carve((size_t)(NDST0 + 1) * 4);
    int* cursor0  = (int*)carve((size_t)NDST0 * 4);
    int* offs1    = (int*)carve((size_t)(NDST1 + 1) * 4);
    int* cursor1  = (int*)carve((size_t)NDST1 * 4);
    int* esrc0    = (int*)carve((size_t)E0 * 4);
    int* esrc1    = (int*)carve((size_t)E1 * 4);
    float* agg0 = (float*)carve((size_t)NDST0 * K_DIM * 4);
    float* xbuf = (float*)carve((size_t)NDST0 * K_DIM * 4);
    float* agg1 = (float*)carve((size_t)NDST1 * K_DIM * 4);
    (void)ws_size; (void)n_in; (void)out_size;

    // zero all degree counters in one shot (ws is poisoned 0xAA before every call)
    hipMemsetAsync(ws, 0, deg_span, stream);

    // degrees (one fused launch)
    {
        long long total = 2LL * E0 + 2LL * E1;
        degree4_kernel<<<(int)((total + 255) / 256), 256, 0, stream>>>(
            src0, dst0, src1, dst1, out_deg0, in_deg0, out_deg1, in_deg1, E0, E1);
    }

    // both exclusive scans in one 2-block launch
    scan2_kernel<<<2, 1024, 0, stream>>>(in_deg0, offs0, cursor0, NDST0,
                                         in_deg1, offs1, cursor1, NDST1);

    // CSR fill (one fused launch)
    fill2_kernel<<<(E0 + E1 + 255) / 256, 256, 0, stream>>>(
        src0, dst0, cursor0, esrc0, E0, src1, dst1, cursor1, esrc1, E1);

    // layer 0: gather-aggregate (norms fused) then GEMM(+bias+relu)
    gather_kernel<<<(NDST0 + 3) / 4, 256, 0, stream>>>(features, esrc0, offs0, out_deg0,
                                                       in_deg0, agg0, NDST0);
    gemm_kernel<256, true><<<NDST0 / 16, 256, 0, stream>>>(agg0, W1, b1, xbuf, NDST0);

    // layer 1: gather-aggregate then GEMM(+bias)
    gather_kernel<<<(NDST1 + 3) / 4, 256, 0, stream>>>(xbuf, esrc1, offs1, out_deg1,
                                                       in_deg1, agg1, NDST1);
    gemm_kernel<128, false><<<NDST1 / 16, 128, 0, stream>>>(agg1, W2, b2, (float*)d_out, NDST1);
}